// Round 1
// baseline (71.231 us; speedup 1.0000x reference)
//
#include <hip/hip_runtime.h>
#include <hip/hip_bf16.h>

// Problem constants (from reference): N=128 nodes, H=2 heads, L=1024.
#define NN 128
#define HH 2
#define LL 1024
#define NH (NN * HH)          // 256 rows
#define NHL (NN * HH * LL)    // 262144 elements per (n,h,l) tensor
#define COLS (HH * LL)        // 2048 columns of the alpha matrix

// Kernel 1: per-(n,h) row — relu, cumsum (-> Ss), linear decay recurrence
// (-> Is -> alpha). One block of 256 threads per row; each thread owns 4
// consecutive elements (float4). Block-level scans via Hillis-Steele in LDS.
// The decay recurrence Is[i] = d*Is[i-1] + s[i] has a constant per-row ratio,
// so the chunk-level scan uses weights D^w with D = d^4 (associative:
// combining windows w gives weight D^w on the older partial).
__global__ __launch_bounds__(256) void row_scan_kernel(
    const float* __restrict__ x, const float* __restrict__ taus,
    const float* __restrict__ r0d, float* __restrict__ out_signal,
    float* __restrict__ ws_alpha, float* __restrict__ ws_ss) {
  const int row = blockIdx.x;   // n*H + h
  const int tid = threadIdx.x;  // 0..255

  const float4* xr = (const float4*)(x + (size_t)row * LL);
  float4 v = xr[tid];
  float s0 = fmaxf(v.x, 0.f);
  float s1 = fmaxf(v.y, 0.f);
  float s2 = fmaxf(v.z, 0.f);
  float s3 = fmaxf(v.w, 0.f);

  const float tau = taus[row];
  const float d = 1.f - 1.f / tau;  // == exp(log(1 - 1/tau))
  const float R0 = r0d[row];

  // thread-local inclusive prefix sums (chunk of 4)
  float c0 = s0, c1 = c0 + s1, c2 = c1 + s2, c3 = c2 + s3;
  // thread-local decay recurrence
  float l0 = s0;
  float l1 = fmaf(d, l0, s1);
  float l2 = fmaf(d, l1, s2);
  float l3 = fmaf(d, l2, s3);

  __shared__ float ssum[256];
  __shared__ float sis[256];

  float vs = c3;  // chunk total sum
  float vi = l3;  // chunk-end recurrence value (zero incoming state)
  ssum[tid] = vs;
  sis[tid] = vi;

  float D = d * d;
  D = D * D;       // d^4: chunk-to-chunk ratio
  float Dp = D;    // D^offset for current step
  for (int off = 1; off < 256; off <<= 1) {
    __syncthreads();
    float ps = (tid >= off) ? ssum[tid - off] : 0.f;
    float pi = (tid >= off) ? sis[tid - off] : 0.f;
    __syncthreads();
    vs += ps;
    vi = fmaf(Dp, pi, vi);
    ssum[tid] = vs;
    sis[tid] = vi;
    Dp *= Dp;
  }
  __syncthreads();
  const float exs = (tid > 0) ? ssum[tid - 1] : 0.f;  // exclusive sum
  const float exi = (tid > 0) ? sis[tid - 1] : 0.f;   // incoming Is state

  // finalize per element
  float cum0 = exs + c0, cum1 = exs + c1, cum2 = exs + c2, cum3 = exs + c3;
  float is0 = fmaf(d, exi, s0);
  float is1 = fmaf(d, is0, s1);
  float is2 = fmaf(d, is1, s2);
  float is3 = fmaf(d, is2, s3);

  float4 sig = make_float4(s0, s1, s2, s3);
  float4 ss = make_float4(1.f - cum0, 1.f - cum1, 1.f - cum2, 1.f - cum3);
  float4 al = make_float4(1.f - __expf(-R0 * is0), 1.f - __expf(-R0 * is1),
                          1.f - __expf(-R0 * is2), 1.f - __expf(-R0 * is3));

  const size_t base = (size_t)row * LL / 4 + tid;
  ((float4*)(out_signal))[base] = sig;   // output 1: signal
  ((float4*)(ws_alpha))[base] = al;
  ((float4*)(ws_ss))[base] = ss;
}

// Kernel 2: Alpha[k,col] = alpha[k,col] + sum_m Amat[k,m]*alpha[m,col];
// predSignal = Alpha * Ss. One thread per output element. A-row reads are
// wave-uniform (scalar path); alpha-column reads are lane-coalesced and
// L2-resident (alpha is 1 MB). First 16384 threads also emit Amat + I.
__global__ __launch_bounds__(256) void mix_kernel(
    const float* __restrict__ Amat, const float* __restrict__ ws_alpha,
    const float* __restrict__ ws_ss, float* __restrict__ pred,
    float* __restrict__ tmatT) {
  const int idx = blockIdx.x * 256 + threadIdx.x;  // 0..262143
  const int k = idx >> 11;      // / COLS
  const int col = idx & (COLS - 1);

  const float* __restrict__ acol = ws_alpha + col;
  const float* __restrict__ arow = Amat + k * NN;
  float acc = ws_alpha[(size_t)k * COLS + col];  // the +I term
#pragma unroll 8
  for (int m = 0; m < NN; ++m) {
    acc = fmaf(arow[m], acol[(size_t)m * COLS], acc);
  }
  pred[idx] = acc * ws_ss[idx];

  if (idx < NN * NN) {
    const int kk = idx >> 7;
    const int mm = idx & (NN - 1);
    tmatT[idx] = Amat[idx] + (kk == mm ? 1.f : 0.f);
  }
}

extern "C" void kernel_launch(void* const* d_in, const int* in_sizes, int n_in,
                              void* d_out, int out_size, void* d_ws,
                              size_t ws_size, hipStream_t stream) {
  const float* x = (const float*)d_in[0];       // (128,2,1024)
  const float* Amat = (const float*)d_in[1];    // (128,128)
  const float* taus = (const float*)d_in[2];    // (128,2)
  const float* r0d = (const float*)d_in[3];     // (128,2)

  float* out = (float*)d_out;
  float* out_pred = out;            // (128,2,1024)
  float* out_signal = out + NHL;    // (128,2,1024)
  float* out_tmatT = out + 2 * NHL; // (128,128) = Amat + I

  float* ws = (float*)d_ws;
  float* ws_alpha = ws;         // NHL floats
  float* ws_ss = ws + NHL;      // NHL floats

  row_scan_kernel<<<NH, 256, 0, stream>>>(x, taus, r0d, out_signal, ws_alpha,
                                          ws_ss);
  mix_kernel<<<NHL / 256, 256, 0, stream>>>(Amat, ws_alpha, ws_ss, out_pred,
                                            out_tmatT);
}

// Round 2
// 70.036 us; speedup vs baseline: 1.0171x; 1.0171x over previous
//
#include <hip/hip_runtime.h>
#include <hip/hip_bf16.h>

// Problem constants (from reference): N=128 nodes, H=2 heads, L=1024.
#define NN 128
#define HH 2
#define LL 1024
#define NH (NN * HH)          // 256 rows
#define NHL (NN * HH * LL)    // 262144 elements per (n,h,l) tensor
#define COLS (HH * LL)        // 2048 columns of the alpha matrix

// Kernel 1: per-(n,h) row — relu, cumsum (-> Ss), linear decay recurrence
// (-> Is -> alpha). One block of 256 threads per row; each thread owns 4
// consecutive elements (float4). Block-level scans via Hillis-Steele in LDS.
// The decay recurrence Is[i] = d*Is[i-1] + s[i] has a constant per-row ratio,
// so the chunk-level scan uses weights D^w with D = d^4.
__global__ __launch_bounds__(256) void row_scan_kernel(
    const float* __restrict__ x, const float* __restrict__ taus,
    const float* __restrict__ r0d, float* __restrict__ out_signal,
    float* __restrict__ ws_alpha, float* __restrict__ ws_ss) {
  const int row = blockIdx.x;   // n*H + h
  const int tid = threadIdx.x;  // 0..255

  const float4* xr = (const float4*)(x + (size_t)row * LL);
  float4 v = xr[tid];
  float s0 = fmaxf(v.x, 0.f);
  float s1 = fmaxf(v.y, 0.f);
  float s2 = fmaxf(v.z, 0.f);
  float s3 = fmaxf(v.w, 0.f);

  const float tau = taus[row];
  const float d = 1.f - 1.f / tau;  // == exp(log(1 - 1/tau))
  const float R0 = r0d[row];

  // thread-local inclusive prefix sums (chunk of 4)
  float c0 = s0, c1 = c0 + s1, c2 = c1 + s2, c3 = c2 + s3;
  // thread-local decay recurrence
  float l0 = s0;
  float l1 = fmaf(d, l0, s1);
  float l2 = fmaf(d, l1, s2);
  float l3 = fmaf(d, l2, s3);

  __shared__ float ssum[256];
  __shared__ float sis[256];

  float vs = c3;  // chunk total sum
  float vi = l3;  // chunk-end recurrence value (zero incoming state)
  ssum[tid] = vs;
  sis[tid] = vi;

  float D = d * d;
  D = D * D;       // d^4: chunk-to-chunk ratio
  float Dp = D;    // D^offset for current step
  for (int off = 1; off < 256; off <<= 1) {
    __syncthreads();
    float ps = (tid >= off) ? ssum[tid - off] : 0.f;
    float pi = (tid >= off) ? sis[tid - off] : 0.f;
    __syncthreads();
    vs += ps;
    vi = fmaf(Dp, pi, vi);
    ssum[tid] = vs;
    sis[tid] = vi;
    Dp *= Dp;
  }
  __syncthreads();
  const float exs = (tid > 0) ? ssum[tid - 1] : 0.f;  // exclusive sum
  const float exi = (tid > 0) ? sis[tid - 1] : 0.f;   // incoming Is state

  // finalize per element
  float cum0 = exs + c0, cum1 = exs + c1, cum2 = exs + c2, cum3 = exs + c3;
  float is0 = fmaf(d, exi, s0);
  float is1 = fmaf(d, is0, s1);
  float is2 = fmaf(d, is1, s2);
  float is3 = fmaf(d, is2, s3);

  float4 sig = make_float4(s0, s1, s2, s3);
  float4 ss = make_float4(1.f - cum0, 1.f - cum1, 1.f - cum2, 1.f - cum3);
  float4 al = make_float4(1.f - __expf(-R0 * is0), 1.f - __expf(-R0 * is1),
                          1.f - __expf(-R0 * is2), 1.f - __expf(-R0 * is3));

  const size_t base = (size_t)row * LL / 4 + tid;
  ((float4*)(out_signal))[base] = sig;   // output 1: signal
  ((float4*)(ws_alpha))[base] = al;
  ((float4*)(ws_ss))[base] = ss;
}

// Kernel 2: Alpha[k,col] = alpha[k,col] + sum_m Amat[k,m]*alpha[m,col];
// predSignal = Alpha * Ss. Each thread computes 4 consecutive cols (float4
// coalesced loads, 4 independent FMA chains). k is block-uniform (each block
// covers 1024 cols of a 2048-col row) -> readfirstlane moves the A-row base
// to an SGPR so arow[] reads go down the scalar pipe.
__global__ __launch_bounds__(256) void mix_kernel(
    const float* __restrict__ Amat, const float* __restrict__ ws_alpha,
    const float* __restrict__ ws_ss, float* __restrict__ pred,
    float* __restrict__ tmatT) {
  const int idx4 = blockIdx.x * 256 + threadIdx.x;  // 0..65535 (float4 units)
  const int e = idx4 << 2;                          // element index
  const int k = __builtin_amdgcn_readfirstlane(e >> 11);  // block-uniform row
  const int c = e & (COLS - 1);                           // column base

  const float* __restrict__ arow = Amat + k * NN;
  const float4* __restrict__ a4 = (const float4*)ws_alpha;
  const int cstride4 = COLS / 4;  // float4 stride between m-rows
  const int c4 = c >> 2;

  float4 acc = a4[k * cstride4 + c4];  // the +I term
#pragma unroll 8
  for (int m = 0; m < NN; ++m) {
    const float w = arow[m];
    const float4 av = a4[m * cstride4 + c4];
    acc.x = fmaf(w, av.x, acc.x);
    acc.y = fmaf(w, av.y, acc.y);
    acc.z = fmaf(w, av.z, acc.z);
    acc.w = fmaf(w, av.w, acc.w);
  }
  const float4 ssv = ((const float4*)ws_ss)[idx4];
  float4 out;
  out.x = acc.x * ssv.x;
  out.y = acc.y * ssv.y;
  out.z = acc.z * ssv.z;
  out.w = acc.w * ssv.w;
  ((float4*)pred)[idx4] = out;

  // tmatT = Amat + I, first 16 blocks (16384 elements / 4 per thread)
  if (e < NN * NN) {
    float4 t = ((const float4*)Amat)[idx4];
    // element e+j: on-diagonal iff (e+j) % 129 == 0  (kk*128+mm, kk==mm)
    if (((e + 0) % (NN + 1)) == 0) t.x += 1.f;
    if (((e + 1) % (NN + 1)) == 0) t.y += 1.f;
    if (((e + 2) % (NN + 1)) == 0) t.z += 1.f;
    if (((e + 3) % (NN + 1)) == 0) t.w += 1.f;
    ((float4*)tmatT)[idx4] = t;
  }
}

extern "C" void kernel_launch(void* const* d_in, const int* in_sizes, int n_in,
                              void* d_out, int out_size, void* d_ws,
                              size_t ws_size, hipStream_t stream) {
  const float* x = (const float*)d_in[0];       // (128,2,1024)
  const float* Amat = (const float*)d_in[1];    // (128,128)
  const float* taus = (const float*)d_in[2];    // (128,2)
  const float* r0d = (const float*)d_in[3];     // (128,2)

  float* out = (float*)d_out;
  float* out_pred = out;            // (128,2,1024)
  float* out_signal = out + NHL;    // (128,2,1024)
  float* out_tmatT = out + 2 * NHL; // (128,128) = Amat + I

  float* ws = (float*)d_ws;
  float* ws_alpha = ws;         // NHL floats
  float* ws_ss = ws + NHL;      // NHL floats

  row_scan_kernel<<<NH, 256, 0, stream>>>(x, taus, r0d, out_signal, ws_alpha,
                                          ws_ss);
  mix_kernel<<<NHL / (256 * 4), 256, 0, stream>>>(Amat, ws_alpha, ws_ss,
                                                  out_pred, out_tmatT);
}

// Round 3
// 68.863 us; speedup vs baseline: 1.0344x; 1.0170x over previous
//
#include <hip/hip_runtime.h>
#include <hip/hip_bf16.h>

// Problem constants (from reference): N=128 nodes, H=2 heads, L=1024.
#define NN 128
#define HH 2
#define LL 1024
#define NH (NN * HH)          // 256 rows
#define NHL (NN * HH * LL)    // 262144 elements per (n,h,l) tensor
#define COLS (HH * LL)        // 2048 columns of the alpha matrix

// Kernel 1: per-(n,h) row — relu, cumsum (-> Ss), linear decay recurrence
// (-> Is -> alpha). One block of 256 threads per row; each thread owns 4
// consecutive elements. Wave-level shuffle scans (no barrier) + one LDS
// exchange of the 4 wave totals (1 barrier) replace the 16-barrier
// Hillis-Steele version. Recurrence Is[i] = d*Is[i-1] + s[i] with uniform
// per-row ratio: chunk ratio D = d^4, wave ratio W = D^64 = d^256.
__global__ __launch_bounds__(256) void row_scan_kernel(
    const float* __restrict__ x, const float* __restrict__ taus,
    const float* __restrict__ r0d, float* __restrict__ out_signal,
    float* __restrict__ ws_alpha, float* __restrict__ ws_ss) {
  const int row = blockIdx.x;   // n*H + h
  const int tid = threadIdx.x;  // 0..255
  const int lane = tid & 63;
  const int wave = tid >> 6;

  const float4* xr = (const float4*)(x + (size_t)row * LL);
  float4 v = xr[tid];
  float s0 = fmaxf(v.x, 0.f);
  float s1 = fmaxf(v.y, 0.f);
  float s2 = fmaxf(v.z, 0.f);
  float s3 = fmaxf(v.w, 0.f);

  const float tau = taus[row];
  const float d = 1.f - 1.f / tau;  // == exp(log(1 - 1/tau))
  const float R0 = r0d[row];

  // thread-local inclusive prefix sums (chunk of 4)
  float c0 = s0, c1 = c0 + s1, c2 = c1 + s2, c3 = c2 + s3;
  // thread-local decay recurrence (zero incoming state)
  float l0 = s0;
  float l1 = fmaf(d, l0, s1);
  float l2 = fmaf(d, l1, s2);
  float l3 = fmaf(d, l2, s3);

  // in-wave weighted inclusive scan over (chunk sum, chunk-end state)
  float vs = c3;
  float vi = l3;
  float D = d * d;
  D = D * D;     // d^4
  float Dp = D;  // D^off
#pragma unroll
  for (int off = 1; off < 64; off <<= 1) {
    float ps = __shfl_up(vs, off);
    float pi = __shfl_up(vi, off);
    if (lane >= off) {
      vs += ps;
      vi = fmaf(Dp, pi, vi);
    }
    Dp *= Dp;
  }
  // Dp == D^64 == wave ratio W

  __shared__ float tw_s[4];
  __shared__ float tw_i[4];
  if (lane == 63) {
    tw_s[wave] = vs;
    tw_i[wave] = vi;
  }
  __syncthreads();

  // wave-incoming totals (sequential combine over earlier waves)
  float S_in = 0.f, I_in = 0.f;
  for (int u = 0; u < wave; ++u) {
    S_in += tw_s[u];
    I_in = fmaf(I_in, Dp, tw_i[u]);  // I = I*W + I_u
  }

  // per-lane exclusive (state at end of previous chunk, within wave)
  float es = __shfl_up(vs, 1);
  float ei = __shfl_up(vi, 1);
  if (lane == 0) {
    es = 0.f;
    ei = 0.f;
  }
  const float exs = S_in + es;
  // wave-incoming state decays D^lane before reaching this chunk (D>0 = d^4)
  const float state = fmaf(I_in, exp2f((float)lane * log2f(D)), ei);

  // finalize per element
  float cum0 = exs + c0, cum1 = exs + c1, cum2 = exs + c2, cum3 = exs + c3;
  float is0 = fmaf(d, state, s0);
  float is1 = fmaf(d, is0, s1);
  float is2 = fmaf(d, is1, s2);
  float is3 = fmaf(d, is2, s3);

  float4 sig = make_float4(s0, s1, s2, s3);
  float4 ss = make_float4(1.f - cum0, 1.f - cum1, 1.f - cum2, 1.f - cum3);
  float4 al = make_float4(1.f - __expf(-R0 * is0), 1.f - __expf(-R0 * is1),
                          1.f - __expf(-R0 * is2), 1.f - __expf(-R0 * is3));

  const size_t base = (size_t)row * LL / 4 + tid;
  ((float4*)(out_signal))[base] = sig;  // output 1: signal
  ((float4*)(ws_alpha))[base] = al;
  ((float4*)(ws_ss))[base] = ss;
}

// Kernel 2: Alpha[k,col] = alpha[k,col] + sum_m Amat[k,m]*alpha[m,col];
// predSignal = Alpha * Ss. k-tiled by 4: each thread computes one column for
// 4 consecutive k rows — each alpha[m,col] load feeds 4 FMAs, cutting L2/L3
// read traffic 4x (134 MB -> 34 MB) while keeping 256 blocks (32 rowgroups x
// 8 colgroups) so traffic stays spread across all CUs' L2 ports. A-row
// weights are block-uniform -> scalar pipe via readfirstlane.
__global__ __launch_bounds__(256) void mix_kernel(
    const float* __restrict__ Amat, const float* __restrict__ ws_alpha,
    const float* __restrict__ ws_ss, float* __restrict__ pred,
    float* __restrict__ tmatT) {
  const int bid = blockIdx.x;  // 0..255
  const int tid = threadIdx.x;
  const int rg = bid >> 3;                                 // 32 rowgroups
  const int cg = bid & 7;                                  // 8 colgroups
  const int col = (cg << 8) + tid;                         // 0..2047
  const int k0 = __builtin_amdgcn_readfirstlane(rg << 2);  // block-uniform

  const float* __restrict__ a0 = Amat + (k0 + 0) * NN;
  const float* __restrict__ a1 = Amat + (k0 + 1) * NN;
  const float* __restrict__ a2 = Amat + (k0 + 2) * NN;
  const float* __restrict__ a3 = Amat + (k0 + 3) * NN;

  // +I term
  float acc0 = ws_alpha[(size_t)(k0 + 0) * COLS + col];
  float acc1 = ws_alpha[(size_t)(k0 + 1) * COLS + col];
  float acc2 = ws_alpha[(size_t)(k0 + 2) * COLS + col];
  float acc3 = ws_alpha[(size_t)(k0 + 3) * COLS + col];

  const float* __restrict__ ac = ws_alpha + col;
#pragma unroll 8
  for (int m = 0; m < NN; ++m) {
    const float av = ac[(size_t)m * COLS];
    acc0 = fmaf(a0[m], av, acc0);
    acc1 = fmaf(a1[m], av, acc1);
    acc2 = fmaf(a2[m], av, acc2);
    acc3 = fmaf(a3[m], av, acc3);
  }

  pred[(size_t)(k0 + 0) * COLS + col] =
      acc0 * ws_ss[(size_t)(k0 + 0) * COLS + col];
  pred[(size_t)(k0 + 1) * COLS + col] =
      acc1 * ws_ss[(size_t)(k0 + 1) * COLS + col];
  pred[(size_t)(k0 + 2) * COLS + col] =
      acc2 * ws_ss[(size_t)(k0 + 2) * COLS + col];
  pred[(size_t)(k0 + 3) * COLS + col] =
      acc3 * ws_ss[(size_t)(k0 + 3) * COLS + col];

  // tmatT = Amat + I (16384 elements, first 4096 flat threads, float4 each)
  const int fid = bid * 256 + tid;
  if (fid < NN * NN / 4) {
    float4 t = ((const float4*)Amat)[fid];
    const int e = fid << 2;
    if (((e + 0) % (NN + 1)) == 0) t.x += 1.f;
    if (((e + 1) % (NN + 1)) == 0) t.y += 1.f;
    if (((e + 2) % (NN + 1)) == 0) t.z += 1.f;
    if (((e + 3) % (NN + 1)) == 0) t.w += 1.f;
    ((float4*)tmatT)[fid] = t;
  }
}

extern "C" void kernel_launch(void* const* d_in, const int* in_sizes, int n_in,
                              void* d_out, int out_size, void* d_ws,
                              size_t ws_size, hipStream_t stream) {
  const float* x = (const float*)d_in[0];     // (128,2,1024)
  const float* Amat = (const float*)d_in[1];  // (128,128)
  const float* taus = (const float*)d_in[2];  // (128,2)
  const float* r0d = (const float*)d_in[3];   // (128,2)

  float* out = (float*)d_out;
  float* out_pred = out;             // (128,2,1024)
  float* out_signal = out + NHL;     // (128,2,1024)
  float* out_tmatT = out + 2 * NHL;  // (128,128) = Amat + I

  float* ws = (float*)d_ws;
  float* ws_alpha = ws;     // NHL floats
  float* ws_ss = ws + NHL;  // NHL floats

  row_scan_kernel<<<NH, 256, 0, stream>>>(x, taus, r0d, out_signal, ws_alpha,
                                          ws_ss);
  mix_kernel<<<256, 256, 0, stream>>>(Amat, ws_alpha, ws_ss, out_pred,
                                      out_tmatT);
}